// Round 1
// baseline (136.629 us; speedup 1.0000x reference)
//
#include <hip/hip_runtime.h>
#include <hip/hip_bf16.h>

#define BATCH 4
#define CHAN 128
#define HGT 96
#define WID 160
#define HW (HGT * WID)
#define THREADS 256

typedef __attribute__((ext_vector_type(8))) short short8;
typedef __attribute__((ext_vector_type(4))) float float4v;

// Output channel index for displacement (dy,dx), matching _displacements(4) order.
// Used only to build the per-block LDS channel-offset table (27 entries).
__device__ __forceinline__ int chan_of(int dy, int dx) {
    if (dy == 0 && dx == 0) return 0;
    if (dx == 0) { int i = dy < 0 ? -dy : dy; return 1 + (i - 1) * 20 + (dy < 0 ? 0 : 1); }
    if (dy == 0) { int i = dx < 0 ? -dx : dx; return 1 + (i - 1) * 20 + (dx < 0 ? 2 : 3); }
    int i = dy < 0 ? -dy : dy;
    int j = dx < 0 ? -dx : dx;
    int s = (dy < 0) ? (dx < 0 ? 0 : 2) : (dx < 0 ? 3 : 1);
    return 1 + (i - 1) * 20 + 4 + (j - 1) * 4 + s;
}

// Packed fp32x2 -> bf16x2 (v_cvt_pk_bf16_f32).
__device__ __forceinline__ unsigned pk2(float a, float b) {
    __hip_bfloat162 h = __float22bfloat162_rn(make_float2(a, b));
    unsigned u;
    __builtin_memcpy(&u, &h, 4);
    return u;
}

union sl_u { uint4 v; short8 s; };

// Staging task = (row, x-quad, c-octet): 8x float4 loads (one per channel of the
// octet), converted to 4 swizzled LDS c-octet slots. 6 rows * 6 xq * 16 oct =
// 576 tasks; tasks 0..255 -> t0, 256..511 -> t1, 512..575 -> t2 (wave 0 only).
// oct = tid&15 keeps consecutive-8-lane groups on 8 distinct XOR'd bank-quads
// (ds_write_b128 conflict-free, matching the measured-0-conflict read side).
#define ST_DECODE(TAG, U)                                                     \
    const int oct##TAG = (U) & 15;                                            \
    const int u4##TAG  = (U) >> 4;                                            \
    const int row##TAG = (u4##TAG * 43) >> 8;      /* /6 for u4 in [0,48) */  \
    const int xq##TAG  = u4##TAG - row##TAG * 6;                              \
    const int gr##TAG  = y0 + dy0 + row##TAG;                                 \
    const int gx##TAG  = x0 - 4 + xq##TAG * 4;     /* 16B aligned */          \
    const bool ok##TAG = ((unsigned)gr##TAG < (unsigned)HGT) &&               \
                         ((unsigned)gx##TAG < (unsigned)WID);                 \
    const int ga##TAG  = tb + (oct##TAG * 8 * HGT + gr##TAG) * WID + gx##TAG;

#define ST_ISSUE(TAG, COND)                                                   \
    _Pragma("unroll")                                                         \
    for (int j = 0; j < 8; ++j)                                               \
        p##TAG[j] = (COND) ? *(const float4v*)(tgt + ga##TAG + j * HW)        \
                           : (float4v){0.f, 0.f, 0.f, 0.f};

#define ST_WRITE(TAG)                                                         \
    _Pragma("unroll")                                                         \
    for (int i = 0; i < 4; ++i) {                                             \
        const int xl = xq##TAG * 4 + i;                                       \
        uint4 val;                                                            \
        val.x = pk2(p##TAG[0][i], p##TAG[1][i]);                              \
        val.y = pk2(p##TAG[2][i], p##TAG[3][i]);                              \
        val.z = pk2(p##TAG[4][i], p##TAG[5][i]);                              \
        val.w = pk2(p##TAG[6][i], p##TAG[7][i]);                              \
        s_b[(row##TAG * 24 + xl) * 16 + (oct##TAG ^ (xl & 15))] = val;        \
    }

__global__ __launch_bounds__(THREADS, 4)
void cost_volume_kernel(const float* __restrict__ src,
                        const float* __restrict__ tgt,
                        float* __restrict__ out) {
    // B tile: 6 rows x 24 x x 16 octets = 2304 slots; sized 2432 so nt=1
    // fragment reads at x up to 31 (band-masked-off columns) stay in-bounds.
    __shared__ __align__(16) uint4 s_b[2432];   // 38912 B -> 4 blocks/CU
    __shared__ int s_tab[27];                   // (dyi,dxi) -> oc*HW

    const int tid  = threadIdx.x;
    const int wv   = tid >> 6;        // wave -> y offset in quad
    const int lane = tid & 63;
    const int q    = lane >> 4;       // quad
    const int ln   = lane & 15;       // m (A) / n (B) lane index

    // XCD-affinity swizzle (validated): blockIdx%8 -> (batch, y-half) slab.
    const int w    = blockIdx.x;      // 0..2879
    const int slab = w & 7;
    const int b    = slab >> 1;
    const int yh   = slab & 1;
    const int r0   = w >> 3;          // 0..359
    const int dyg  = r0 % 3;
    const int t    = r0 / 3;          // 0..119
    const int x0   = (t % 10) * 16;
    const int y0   = yh * 48 + (t / 10) * 4;
    const int dy0  = dyg * 3 - 4;     // dys: dy0 .. dy0+2

    // Channel-offset table (replaces per-slot branchy chan_of in the epilogue).
    if (tid < 27) s_tab[tid] = chan_of(dy0 + tid / 9, tid % 9 - 4) * HW;

    const int tb = b * CHAN * HGT * WID;

    ST_DECODE(0, tid)
    ST_DECODE(1, tid + 256)
    ST_DECODE(2, tid + 512)
    const bool has2 = tid < 64;

    float4v p0[8], p1[8], p2[8];

    // ---- in-flight schedule: t0 | A | t1 issued before first wait ----
    ST_ISSUE(0, ok0)

    // A fragments: issue all 32 channel-strided loads (payload held in regs).
    const int y  = y0 + wv;
    const int sbase = (b * CHAN * HGT + y) * WID + x0 + ln + q * 8 * HW;
    float apay[32];
    #pragma unroll
    for (int ks = 0; ks < 4; ++ks)
        #pragma unroll
        for (int j = 0; j < 8; ++j)
            apay[ks * 8 + j] = src[sbase + (ks * 32 + j) * HW];

    ST_ISSUE(1, ok1)

    ST_WRITE(0)                 // waits t0 only; A + t1 stay in flight
    ST_ISSUE(2, has2 && ok2)    // t0 payload freed -> issue tail task
    // convert A (its loads drained alongside t0's wait -> no extra stall)
    short8 afr[4];
    #pragma unroll
    for (int ks = 0; ks < 4; ++ks) {
        sl_u f;
        f.v.x = pk2(apay[ks * 8 + 0], apay[ks * 8 + 1]);
        f.v.y = pk2(apay[ks * 8 + 2], apay[ks * 8 + 3]);
        f.v.z = pk2(apay[ks * 8 + 4], apay[ks * 8 + 5]);
        f.v.w = pk2(apay[ks * 8 + 6], apay[ks * 8 + 7]);
        afr[ks] = f.s;
    }
    ST_WRITE(1)
    if (has2) { ST_WRITE(2) }

    __syncthreads();

    // ---- compute + per-dy epilogue: 24 ds_read_b128 + 24 MFMA per wave ----
    const float inv = 1.0f / 81.0f;
    const int obase = (b * 81 * HGT + y) * WID + x0;
    #pragma unroll
    for (int dyi = 0; dyi < 3; ++dyi) {
        const int rr = wv + dyi;              // LDS row = (y+dy) - (y0+dy0)
        float4v a0 = (float4v){0.f, 0.f, 0.f, 0.f};
        float4v a1 = (float4v){0.f, 0.f, 0.f, 0.f};
        #pragma unroll
        for (int ks = 0; ks < 4; ++ks) {
            sl_u b0;   // nt=0: x index = ln (x&15 = ln)
            b0.v = s_b[(rr * 24 + ln) * 16 + ((q + ks * 4) ^ ln)];
            a0 = __builtin_amdgcn_mfma_f32_16x16x32_bf16(afr[ks], b0.s, a0, 0, 0, 0);
        }
        #pragma unroll
        for (int ks = 0; ks < 4; ++ks) {
            sl_u b1;   // nt=1: x index = 16+ln ((16+ln)&15 = ln)
            b1.v = s_b[(rr * 24 + 16 + ln) * 16 + ((q + ks * 4) ^ ln)];
            a1 = __builtin_amdgcn_mfma_f32_16x16x32_bf16(afr[ks], b1.s, a1, 0, 0, 0);
        }
        // band extraction from C/D layout (col=n=ln, row=m=q*4+reg)
        #pragma unroll
        for (int reg = 0; reg < 4; ++reg) {
            const int m = q * 4 + reg;        // output x = x0 + m
            const int t0x = ln - m;           // dx+4 for nt=0
            if ((unsigned)t0x <= 8u)
                out[obase + s_tab[dyi * 9 + t0x] + m] = a0[reg] * inv;
            const int t1x = ln + 16 - m;      // dx+4 for nt=1
            if ((unsigned)t1x <= 8u)
                out[obase + s_tab[dyi * 9 + t1x] + m] = a1[reg] * inv;
        }
    }
}

extern "C" void kernel_launch(void* const* d_in, const int* in_sizes, int n_in,
                              void* d_out, int out_size, void* d_ws, size_t ws_size,
                              hipStream_t stream) {
    const float* src = (const float*)d_in[0];
    const float* tgt = (const float*)d_in[1];
    float* out = (float*)d_out;
    cost_volume_kernel<<<dim3(2880, 1, 1), dim3(THREADS, 1, 1), 0, stream>>>(src, tgt, out);
}

// Round 2
// 120.222 us; speedup vs baseline: 1.1365x; 1.1365x over previous
//
#include <hip/hip_runtime.h>
#include <hip/hip_bf16.h>

#define BATCH 4
#define CHAN 128
#define HGT 96
#define WID 160
#define HW (HGT * WID)
#define THREADS 256
#define TENSOR_ELEMS (BATCH * CHAN * HGT * WID)
#define WS_NEED ((size_t)(2 * (size_t)TENSOR_ELEMS * 2))

typedef __attribute__((ext_vector_type(8))) short short8;
typedef __attribute__((ext_vector_type(4))) float float4v;

// Output channel index for displacement (dy,dx), matching _displacements(4) order.
__device__ __forceinline__ int chan_of(int dy, int dx) {
    if (dy == 0 && dx == 0) return 0;
    if (dx == 0) { int i = dy < 0 ? -dy : dy; return 1 + (i - 1) * 20 + (dy < 0 ? 0 : 1); }
    if (dy == 0) { int i = dx < 0 ? -dx : dx; return 1 + (i - 1) * 20 + (dx < 0 ? 2 : 3); }
    int i = dy < 0 ? -dy : dy;
    int j = dx < 0 ? -dx : dx;
    int s = (dy < 0) ? (dx < 0 ? 0 : 2) : (dx < 0 ? 3 : 1);
    return 1 + (i - 1) * 20 + 4 + (j - 1) * 4 + s;
}

// Packed fp32x2 -> bf16x2 (v_cvt_pk_bf16_f32).
__device__ __forceinline__ unsigned pk2(float a, float b) {
    __hip_bfloat162 h = __float22bfloat162_rn(make_float2(a, b));
    unsigned u;
    __builtin_memcpy(&u, &h, 4);
    return u;
}

union sl_u { uint4 v; short8 s; };

// ---------------------------------------------------------------------------
// Pre-pass: NCHW f32 -> NHWC bf16 for both tensors (into d_ws).
// Block = (tensor, b, y, 64-pixel x-block). Coalesced f32 reads (lanes span x),
// LDS-transposed as packed bf16 pairs, fully coalesced 16B writes.
// LDS [64 cpair][65] u32: phase-1 writes row-wise (conflict-free), phase-2
// reads column-wise (stride 65 = bank-rotating, 2-way only = free).
// ---------------------------------------------------------------------------
__global__ __launch_bounds__(THREADS)
void nhwc_bf16_kernel(const float* __restrict__ src,
                      const float* __restrict__ tgt,
                      ushort* __restrict__ ws) {
    __shared__ unsigned s_t[64][65];
    int r = blockIdx.x;                 // 3 * 96 * 4 * 2 = 2304
    const int xb = r % 3; r /= 3;
    const int y  = r % HGT; r /= HGT;
    const int b  = r % BATCH; r /= BATCH;
    const float* in = r ? tgt : src;
    ushort* op0 = ws + (size_t)r * TENSOR_ELEMS;
    const int x0 = xb * 64;
    const int npx = (x0 + 64 <= WID) ? 64 : (WID - x0);   // 64 or 32

    const int t  = threadIdx.x;
    const int x1 = t & 63, cp0 = t >> 6;
    if (x1 < npx) {
        const int base = (b * CHAN * HGT + y) * WID + x0 + x1;  // channel 0
        #pragma unroll
        for (int i = 0; i < 16; ++i) {
            const int cp = cp0 + i * 4;                 // channel pair 0..63
            float a = in[base + (2 * cp) * HW];
            float c = in[base + (2 * cp + 1) * HW];
            s_t[cp][x1] = pk2(a, c);
        }
    }
    __syncthreads();
    const int x2 = t >> 2, g = t & 3;
    if (x2 < npx) {
        ushort* op = op0 + ((size_t)(b * HGT + y) * WID + x0 + x2) * CHAN + g * 32;
        #pragma unroll
        for (int k = 0; k < 4; ++k) {
            uint4 v;
            v.x = s_t[g * 16 + k * 4 + 0][x2];
            v.y = s_t[g * 16 + k * 4 + 1][x2];
            v.z = s_t[g * 16 + k * 4 + 2][x2];
            v.w = s_t[g * 16 + k * 4 + 3][x2];
            *(uint4*)(op + k * 8) = v;
        }
    }
}

// ---------------------------------------------------------------------------
// Main kernel (NHWC bf16 inputs): B tile staged via global_load_lds DMA
// (no VGPR payload, no cvt, no ds_write, single vmcnt drain at the barrier).
// XOR bank swizzle moved to the GLOBAL source octet (linear LDS dest +
// inverse-swizzled source + swizzled read = guide rule 21). Read side and
// epilogue identical to the measured-0-conflict R0/R1 kernels.
// ---------------------------------------------------------------------------
__global__ __launch_bounds__(THREADS)
void cost_volume_mfma(const ushort* __restrict__ srcT,
                      const ushort* __restrict__ tgtT,
                      float* __restrict__ out) {
    __shared__ __align__(16) uint4 s_b[2432];   // 38912 B -> 4 blocks/CU
    __shared__ int s_tab[27];                   // (dyi,dxi) -> oc*HW

    const int tid  = threadIdx.x;
    const int wv   = tid >> 6;
    const int lane = tid & 63;
    const int q    = lane >> 4;
    const int ln   = lane & 15;

    // XCD-affinity swizzle: blockIdx%8 -> (batch, y-half) slab.
    const int w    = blockIdx.x;      // 0..2879
    const int slab = w & 7;
    const int b    = slab >> 1;
    const int yh   = slab & 1;
    const int r0   = w >> 3;
    const int dyg  = r0 % 3;
    const int t    = r0 / 3;
    const int x0   = (t % 10) * 16;
    const int y0   = yh * 48 + (t / 10) * 4;
    const int dy0  = dyg * 3 - 4;

    if (tid < 27) s_tab[tid] = chan_of(dy0 + tid / 9, tid % 9 - 4) * HW;

    // ---- stage B: 2304 slots, 9 DMA loads/thread, slot u = (row*24+x)*16+j
    // slot j holds octet j^(x&15); read for octet o fetches slot o^(x&15).
    const ushort* tbase = tgtT + (size_t)b * HGT * WID * CHAN;
    #pragma unroll
    for (int k = 0; k < 9; ++k) {
        const int u   = k * THREADS + tid;   // == wave base + lane
        const int j   = u & 15;
        const int v16 = u >> 4;              // row*24 + x, 0..143
        const int row = v16 / 24;
        const int x   = v16 - row * 24;
        const int gr  = y0 + dy0 + row;
        const int gx  = x0 - 4 + x;
        const int oct = j ^ (x & 15);
        // wave-uniform LDS base (lane*16 added by HW)
        unsigned* lp = (unsigned*)&s_b[k * THREADS + (tid & ~63)];
        if (((unsigned)gr < (unsigned)HGT) && ((unsigned)gx < (unsigned)WID)) {
            const unsigned* gp =
                (const unsigned*)(tbase + ((gr * WID + gx) * CHAN + oct * 8));
            __builtin_amdgcn_global_load_lds(gp, lp, 16, 0, 0);
        } else {
            s_b[u] = make_uint4(0u, 0u, 0u, 0u);   // disjoint from DMA targets
        }
    }

    // ---- A fragments: 4 x 16B contiguous loads (NHWC), no conversion ----
    const int y = y0 + wv;
    const ushort* abase =
        srcT + ((size_t)(b * HGT + y) * WID + x0 + ln) * CHAN + q * 8;
    short8 afr[4];
    #pragma unroll
    for (int ks = 0; ks < 4; ++ks)
        afr[ks] = *(const short8*)(abase + ks * 32);

    __syncthreads();   // drains DMA (vmcnt) + zero-fill (lgkmcnt)

    // ---- compute + per-dy epilogue: 24 ds_read_b128 + 24 MFMA per wave ----
    const float inv = 1.0f / 81.0f;
    const int obase = (b * 81 * HGT + y) * WID + x0;
    #pragma unroll
    for (int dyi = 0; dyi < 3; ++dyi) {
        const int rr = wv + dyi;
        float4v a0 = (float4v){0.f, 0.f, 0.f, 0.f};
        float4v a1 = (float4v){0.f, 0.f, 0.f, 0.f};
        #pragma unroll
        for (int ks = 0; ks < 4; ++ks) {
            sl_u b0;   // nt=0: x = ln
            b0.v = s_b[(rr * 24 + ln) * 16 + ((q + ks * 4) ^ ln)];
            a0 = __builtin_amdgcn_mfma_f32_16x16x32_bf16(afr[ks], b0.s, a0, 0, 0, 0);
        }
        #pragma unroll
        for (int ks = 0; ks < 4; ++ks) {
            sl_u b1;   // nt=1: x = 16+ln
            b1.v = s_b[(rr * 24 + 16 + ln) * 16 + ((q + ks * 4) ^ ln)];
            a1 = __builtin_amdgcn_mfma_f32_16x16x32_bf16(afr[ks], b1.s, a1, 0, 0, 0);
        }
        #pragma unroll
        for (int reg = 0; reg < 4; ++reg) {
            const int m = q * 4 + reg;
            const int t0x = ln - m;           // dx+4 for nt=0
            if ((unsigned)t0x <= 8u)
                out[obase + s_tab[dyi * 9 + t0x] + m] = a0[reg] * inv;
            const int t1x = ln + 16 - m;      // dx+4 for nt=1
            if ((unsigned)t1x <= 8u)
                out[obase + s_tab[dyi * 9 + t1x] + m] = a1[reg] * inv;
        }
    }
}

// ---------------------------------------------------------------------------
// Fallback (ws too small): R1 single-kernel path, correctness-safe.
// ---------------------------------------------------------------------------
#define ST_DECODE(TAG, U)                                                     \
    const int oct##TAG = (U) & 15;                                            \
    const int u4##TAG  = (U) >> 4;                                            \
    const int row##TAG = (u4##TAG * 43) >> 8;                                 \
    const int xq##TAG  = u4##TAG - row##TAG * 6;                              \
    const int gr##TAG  = y0 + dy0 + row##TAG;                                 \
    const int gx##TAG  = x0 - 4 + xq##TAG * 4;                                \
    const bool ok##TAG = ((unsigned)gr##TAG < (unsigned)HGT) &&               \
                         ((unsigned)gx##TAG < (unsigned)WID);                 \
    const int ga##TAG  = tb + (oct##TAG * 8 * HGT + gr##TAG) * WID + gx##TAG;

#define ST_ISSUE(TAG, COND)                                                   \
    _Pragma("unroll")                                                         \
    for (int j = 0; j < 8; ++j)                                               \
        p##TAG[j] = (COND) ? *(const float4v*)(tgt + ga##TAG + j * HW)        \
                           : (float4v){0.f, 0.f, 0.f, 0.f};

#define ST_WRITE(TAG)                                                         \
    _Pragma("unroll")                                                         \
    for (int i = 0; i < 4; ++i) {                                             \
        const int xl = xq##TAG * 4 + i;                                       \
        uint4 val;                                                            \
        val.x = pk2(p##TAG[0][i], p##TAG[1][i]);                              \
        val.y = pk2(p##TAG[2][i], p##TAG[3][i]);                              \
        val.z = pk2(p##TAG[4][i], p##TAG[5][i]);                              \
        val.w = pk2(p##TAG[6][i], p##TAG[7][i]);                              \
        s_b[(row##TAG * 24 + xl) * 16 + (oct##TAG ^ (xl & 15))] = val;        \
    }

__global__ __launch_bounds__(THREADS, 4)
void cost_volume_fallback(const float* __restrict__ src,
                          const float* __restrict__ tgt,
                          float* __restrict__ out) {
    __shared__ __align__(16) uint4 s_b[2432];
    __shared__ int s_tab[27];

    const int tid  = threadIdx.x;
    const int wv   = tid >> 6;
    const int lane = tid & 63;
    const int q    = lane >> 4;
    const int ln   = lane & 15;

    const int w    = blockIdx.x;
    const int slab = w & 7;
    const int b    = slab >> 1;
    const int yh   = slab & 1;
    const int r0   = w >> 3;
    const int dyg  = r0 % 3;
    const int t    = r0 / 3;
    const int x0   = (t % 10) * 16;
    const int y0   = yh * 48 + (t / 10) * 4;
    const int dy0  = dyg * 3 - 4;

    if (tid < 27) s_tab[tid] = chan_of(dy0 + tid / 9, tid % 9 - 4) * HW;

    const int tb = b * CHAN * HGT * WID;

    ST_DECODE(0, tid)
    ST_DECODE(1, tid + 256)
    ST_DECODE(2, tid + 512)
    const bool has2 = tid < 64;

    float4v p0[8], p1[8], p2[8];
    ST_ISSUE(0, ok0)

    const int y  = y0 + wv;
    const int sbase = (b * CHAN * HGT + y) * WID + x0 + ln + q * 8 * HW;
    float apay[32];
    #pragma unroll
    for (int ks = 0; ks < 4; ++ks)
        #pragma unroll
        for (int j = 0; j < 8; ++j)
            apay[ks * 8 + j] = src[sbase + (ks * 32 + j) * HW];

    ST_ISSUE(1, ok1)
    ST_WRITE(0)
    ST_ISSUE(2, has2 && ok2)
    short8 afr[4];
    #pragma unroll
    for (int ks = 0; ks < 4; ++ks) {
        sl_u f;
        f.v.x = pk2(apay[ks * 8 + 0], apay[ks * 8 + 1]);
        f.v.y = pk2(apay[ks * 8 + 2], apay[ks * 8 + 3]);
        f.v.z = pk2(apay[ks * 8 + 4], apay[ks * 8 + 5]);
        f.v.w = pk2(apay[ks * 8 + 6], apay[ks * 8 + 7]);
        afr[ks] = f.s;
    }
    ST_WRITE(1)
    if (has2) { ST_WRITE(2) }

    __syncthreads();

    const float inv = 1.0f / 81.0f;
    const int obase = (b * 81 * HGT + y) * WID + x0;
    #pragma unroll
    for (int dyi = 0; dyi < 3; ++dyi) {
        const int rr = wv + dyi;
        float4v a0 = (float4v){0.f, 0.f, 0.f, 0.f};
        float4v a1 = (float4v){0.f, 0.f, 0.f, 0.f};
        #pragma unroll
        for (int ks = 0; ks < 4; ++ks) {
            sl_u b0;
            b0.v = s_b[(rr * 24 + ln) * 16 + ((q + ks * 4) ^ ln)];
            a0 = __builtin_amdgcn_mfma_f32_16x16x32_bf16(afr[ks], b0.s, a0, 0, 0, 0);
        }
        #pragma unroll
        for (int ks = 0; ks < 4; ++ks) {
            sl_u b1;
            b1.v = s_b[(rr * 24 + 16 + ln) * 16 + ((q + ks * 4) ^ ln)];
            a1 = __builtin_amdgcn_mfma_f32_16x16x32_bf16(afr[ks], b1.s, a1, 0, 0, 0);
        }
        #pragma unroll
        for (int reg = 0; reg < 4; ++reg) {
            const int m = q * 4 + reg;
            const int t0x = ln - m;
            if ((unsigned)t0x <= 8u)
                out[obase + s_tab[dyi * 9 + t0x] + m] = a0[reg] * inv;
            const int t1x = ln + 16 - m;
            if ((unsigned)t1x <= 8u)
                out[obase + s_tab[dyi * 9 + t1x] + m] = a1[reg] * inv;
        }
    }
}

extern "C" void kernel_launch(void* const* d_in, const int* in_sizes, int n_in,
                              void* d_out, int out_size, void* d_ws, size_t ws_size,
                              hipStream_t stream) {
    const float* src = (const float*)d_in[0];
    const float* tgt = (const float*)d_in[1];
    float* out = (float*)d_out;
    if (d_ws && ws_size >= WS_NEED) {
        ushort* ws = (ushort*)d_ws;
        nhwc_bf16_kernel<<<dim3(2304, 1, 1), dim3(THREADS, 1, 1), 0, stream>>>(src, tgt, ws);
        cost_volume_mfma<<<dim3(2880, 1, 1), dim3(THREADS, 1, 1), 0, stream>>>(
            ws, ws + TENSOR_ELEMS, out);
    } else {
        cost_volume_fallback<<<dim3(2880, 1, 1), dim3(THREADS, 1, 1), 0, stream>>>(src, tgt, out);
    }
}